// Round 1
// baseline (159.298 us; speedup 1.0000x reference)
//
#include <hip/hip_runtime.h>
#include <hip/hip_bf16.h>
#include <stdint.h>

// ---------------------------------------------------------------------------
// Decoder_10110353014984: LIF multistep (T=4) + linear head
//   x: [4,64,196,512] f32, W: [1000,512] f32, b: [1000] f32
//   y: [4,64,196,1000] f32
// Plan: (1) LIF -> bf16 spikes in ws, (2) W -> bf16 (padded to 1024 rows),
//       (3) MFMA GEMM  y[m,c] = sum_d S[m,d]*W[c,d] + b[c]
// ---------------------------------------------------------------------------

typedef __attribute__((ext_vector_type(8))) short bf16x8;
typedef __attribute__((ext_vector_type(4))) float f32x4;

#define AS1(p) ((const __attribute__((address_space(1))) void*)(p))
#define AS3(p) ((__attribute__((address_space(3))) void*)(p))

static constexpr int     T_STEPS = 4;
static constexpr int64_t ESP     = 6422528;   // B*N*D = 64*196*512
static constexpr int     K_DIM   = 512;
static constexpr int     C_DIM   = 1000;
static constexpr int     C_PAD   = 1024;
static constexpr int64_t M_ROWS  = 50176;     // T*B*N

__device__ __forceinline__ unsigned short f2bf(float f) {
  unsigned int u = __float_as_uint(f);
  u += 0x7FFFu + ((u >> 16) & 1u);            // round-to-nearest-even
  return (unsigned short)(u >> 16);
}

// ---------------------------------------------------------------------------
// Kernel 1: LIF dynamics. Each thread owns 4 consecutive (b,n,d) elements,
// loops over T. Bit-exact vs reference: v += (x - v) * 0.5f (mul by 0.5 is
// exact, so FMA contraction cannot change the result); spike iff v >= 1.0f.
// ---------------------------------------------------------------------------
__global__ void lif_kernel(const float* __restrict__ x,
                           unsigned short* __restrict__ S) {
  const int64_t stride = (int64_t)gridDim.x * blockDim.x;
  const int64_t nquads = ESP / 4;
  for (int64_t q = (int64_t)blockIdx.x * blockDim.x + threadIdx.x;
       q < nquads; q += stride) {
    const int64_t s0 = q << 2;
    float v[4] = {0.f, 0.f, 0.f, 0.f};
#pragma unroll
    for (int t = 0; t < T_STEPS; ++t) {
      const float4 xt = *(const float4*)(x + (int64_t)t * ESP + s0);
      const float xa[4] = {xt.x, xt.y, xt.z, xt.w};
      ushort4 sp;
      unsigned short* spp = &sp.x;
#pragma unroll
      for (int j = 0; j < 4; ++j) {
        v[j] = v[j] + (xa[j] - v[j]) * 0.5f;   // charge
        const bool fire = (v[j] >= 1.0f);
        spp[j] = fire ? (unsigned short)0x3F80 : (unsigned short)0; // bf16 1/0
        if (fire) v[j] = 0.0f;                 // hard reset
      }
      *(ushort4*)(S + (int64_t)t * ESP + s0) = sp;
    }
  }
}

// ---------------------------------------------------------------------------
// Kernel 2: W f32[1000,512] -> bf16[1024,512], rows 1000..1023 zeroed.
// ---------------------------------------------------------------------------
__global__ void wconv_kernel(const float* __restrict__ W,
                             unsigned short* __restrict__ Wb) {
  const int idx = blockIdx.x * blockDim.x + threadIdx.x;  // 0..131071
  const int64_t base = (int64_t)idx * 4;
  const int row = (int)(base >> 9);
  ushort4 o;
  if (row < C_DIM) {
    const float4 wv = *(const float4*)(W + base);
    o.x = f2bf(wv.x); o.y = f2bf(wv.y); o.z = f2bf(wv.z); o.w = f2bf(wv.w);
  } else {
    o.x = o.y = o.z = o.w = 0;
  }
  *(ushort4*)(Wb + base) = o;
}

// ---------------------------------------------------------------------------
// Kernel 3: GEMM  Y[m,c] = sum_d S[m,d] * Wb[c,d] + b[c]
// m97 structure: 128x128 tile, BK=64, 4 waves (2x2), each wave 64x64 via
// 4x4 frags of mfma_f32_16x16x32_bf16. global_load_lds width 16 with
// pre-swizzled global source; ds_read_b128 with matching XOR swizzle
// (byte ^= (row&7)<<4) -> conflict-free.
// ---------------------------------------------------------------------------
__global__ __launch_bounds__(256) void gemm_kernel(
    const unsigned short* __restrict__ S,
    const unsigned short* __restrict__ Wb,
    const float* __restrict__ bias,
    float* __restrict__ Y) {
  __shared__ __attribute__((aligned(16))) unsigned short As[128 * 64];
  __shared__ __attribute__((aligned(16))) unsigned short Bs[128 * 64];

  const int tid  = threadIdx.x;
  const int lane = tid & 63;
  const int w    = tid >> 6;
  const int wr   = w >> 1;        // wave row (0..1)
  const int wc   = w & 1;         // wave col (0..1)
  const int64_t row0 = (int64_t)blockIdx.x * 128;
  const int     c0   = blockIdx.y * 128;

  // staging: per call a wave writes 8 rows x 128B linearly into LDS;
  // swizzle is applied on the GLOBAL source address (rule: both-sides).
  const int srow = lane >> 3;                       // 0..7
  const int skb  = ((lane & 7) ^ srow) << 4;        // swizzled byte col in row

  const char* Sg = (const char*)S;
  const char* Wg = (const char*)Wb;
  char* Ab = (char*)As;
  char* Bb = (char*)Bs;

  f32x4 acc[4][4] = {};

  for (int k0 = 0; k0 < K_DIM; k0 += 64) {
#pragma unroll
    for (int call = 0; call < 4; ++call) {
      const int rr = w * 32 + call * 8;             // uniform row base (mult of 8)
      const int r  = rr + srow;
      __builtin_amdgcn_global_load_lds(
          AS1(Sg + ((row0 + r) * (int64_t)K_DIM + k0) * 2 + skb),
          AS3(Ab + rr * 128), 16, 0, 0);
      __builtin_amdgcn_global_load_lds(
          AS1(Wg + (((int64_t)(c0 + r)) * K_DIM + k0) * 2 + skb),
          AS3(Bb + rr * 128), 16, 0, 0);
    }
    __syncthreads();

#pragma unroll
    for (int kk = 0; kk < 2; ++kk) {
      const int lr = lane & 15;
      const int kb = kk * 64 + (lane >> 4) * 16;    // byte offset of k-octet
      bf16x8 afr[4], bfr[4];
#pragma unroll
      for (int mi = 0; mi < 4; ++mi) {
        const int r = wr * 64 + mi * 16 + lr;
        afr[mi] = *(const bf16x8*)(Ab + r * 128 + (kb ^ ((r & 7) << 4)));
      }
#pragma unroll
      for (int nj = 0; nj < 4; ++nj) {
        const int r = wc * 64 + nj * 16 + lr;
        bfr[nj] = *(const bf16x8*)(Bb + r * 128 + (kb ^ ((r & 7) << 4)));
      }
#pragma unroll
      for (int mi = 0; mi < 4; ++mi)
#pragma unroll
        for (int nj = 0; nj < 4; ++nj)
          acc[mi][nj] = __builtin_amdgcn_mfma_f32_16x16x32_bf16(
              afr[mi], bfr[nj], acc[mi][nj], 0, 0, 0);
    }
    __syncthreads();
  }

  // epilogue: C/D layout col = lane&15, row = (lane>>4)*4 + reg
  const int lr = lane & 15;
#pragma unroll
  for (int nj = 0; nj < 4; ++nj) {
    const int c = c0 + wc * 64 + nj * 16 + lr;
    if (c >= C_DIM) continue;
    const float bv = bias[c];
#pragma unroll
    for (int mi = 0; mi < 4; ++mi) {
      const int64_t rbase = row0 + wr * 64 + mi * 16 + (lane >> 4) * 4;
#pragma unroll
      for (int r = 0; r < 4; ++r) {
        Y[(rbase + r) * (int64_t)C_DIM + c] = acc[mi][nj][r] + bv;
      }
    }
  }
}

// ---------------------------------------------------------------------------
extern "C" void kernel_launch(void* const* d_in, const int* in_sizes, int n_in,
                              void* d_out, int out_size, void* d_ws, size_t ws_size,
                              hipStream_t stream) {
  const float* x = (const float*)d_in[0];
  const float* W = (const float*)d_in[1];
  const float* b = (const float*)d_in[2];
  float* Y = (float*)d_out;

  unsigned short* S  = (unsigned short*)d_ws;            // 50176*512 bf16 = 51.4 MB
  unsigned short* Wb = S + (size_t)M_ROWS * K_DIM;       // 1024*512 bf16  =  1.0 MB

  hipLaunchKernelGGL(wconv_kernel, dim3(512), dim3(256), 0, stream, W, Wb);
  hipLaunchKernelGGL(lif_kernel, dim3(2048), dim3(256), 0, stream, x, S);
  hipLaunchKernelGGL(gemm_kernel, dim3(392, 8), dim3(256), 0, stream, S, Wb, b, Y);
}

// Round 2
// 157.940 us; speedup vs baseline: 1.0086x; 1.0086x over previous
//
#include <hip/hip_runtime.h>
#include <hip/hip_bf16.h>
#include <stdint.h>

// ---------------------------------------------------------------------------
// Decoder_10110353014984: LIF multistep (T=4) + linear head
//   x: [4,64,196,512] f32, W: [1000,512] f32, b: [1000] f32
//   y: [4,64,196,1000] f32
// R2: GEMM rebuilt as 256x256 tile, BK=64, 8 waves, double-buffered 128KB LDS,
//     4-phase interleave per K-tile (T3+T4), setprio around MFMA (T5),
//     XOR LDS swizzle via pre-swizzled global source (T2), XCD-aware block
//     swizzle grouping the 4 N-tiles of an M-tile on one XCD (T1).
// ---------------------------------------------------------------------------

typedef __attribute__((ext_vector_type(8))) short bf16x8;
typedef __attribute__((ext_vector_type(4))) float f32x4;

#define AS1(p) ((const __attribute__((address_space(1))) void*)(p))
#define AS3(p) ((__attribute__((address_space(3))) void*)(p))

static constexpr int     T_STEPS = 4;
static constexpr int64_t ESP     = 6422528;   // B*N*D = 64*196*512
static constexpr int     K_DIM   = 512;
static constexpr int     C_DIM   = 1000;
static constexpr int64_t M_ROWS  = 50176;     // T*B*N

__device__ __forceinline__ unsigned short f2bf(float f) {
  unsigned int u = __float_as_uint(f);
  u += 0x7FFFu + ((u >> 16) & 1u);            // round-to-nearest-even
  return (unsigned short)(u >> 16);
}

// ---------------------------------------------------------------------------
// Kernel 1: LIF dynamics -> bf16 spikes. Bit-exact vs reference:
// v += (x - v) * 0.5f (exact *0.5), spike iff v >= 1.0f, hard reset.
// ---------------------------------------------------------------------------
__global__ void lif_kernel(const float* __restrict__ x,
                           unsigned short* __restrict__ S) {
  const int64_t stride = (int64_t)gridDim.x * blockDim.x;
  const int64_t nquads = ESP / 4;
  for (int64_t q = (int64_t)blockIdx.x * blockDim.x + threadIdx.x;
       q < nquads; q += stride) {
    const int64_t s0 = q << 2;
    float v[4] = {0.f, 0.f, 0.f, 0.f};
#pragma unroll
    for (int t = 0; t < T_STEPS; ++t) {
      const float4 xt = *(const float4*)(x + (int64_t)t * ESP + s0);
      const float xa[4] = {xt.x, xt.y, xt.z, xt.w};
      ushort4 sp;
      unsigned short* spp = &sp.x;
#pragma unroll
      for (int j = 0; j < 4; ++j) {
        v[j] = v[j] + (xa[j] - v[j]) * 0.5f;   // charge
        const bool fire = (v[j] >= 1.0f);
        spp[j] = fire ? (unsigned short)0x3F80 : (unsigned short)0; // bf16 1/0
        if (fire) v[j] = 0.0f;                 // hard reset
      }
      *(ushort4*)(S + (int64_t)t * ESP + s0) = sp;
    }
  }
}

// ---------------------------------------------------------------------------
// Kernel 2: W f32[1000,512] -> bf16[1024,512], rows 1000..1023 zeroed.
// ---------------------------------------------------------------------------
__global__ void wconv_kernel(const float* __restrict__ W,
                             unsigned short* __restrict__ Wb) {
  const int idx = blockIdx.x * blockDim.x + threadIdx.x;  // 0..131071
  const int64_t base = (int64_t)idx * 4;
  const int row = (int)(base >> 9);
  ushort4 o;
  if (row < C_DIM) {
    const float4 wv = *(const float4*)(W + base);
    o.x = f2bf(wv.x); o.y = f2bf(wv.y); o.z = f2bf(wv.z); o.w = f2bf(wv.w);
  } else {
    o.x = o.y = o.z = o.w = 0;
  }
  *(ushort4*)(Wb + base) = o;
}

// ---------------------------------------------------------------------------
// Kernel 3: GEMM  Y[m,c] = sum_d S[m,d] * Wb[c,d] + b[c]
// 256x256 tile, BK=64, 512 threads (8 waves, 2Mx4N), dbuf LDS 128KB.
// Per K-tile: 4 phases, each {ds_read frag subtile | 2x global_load_lds
// prefetch of next K-tile -> s_barrier -> lgkmcnt(0) -> setprio(1) +
// 16 MFMA -> s_barrier}; one __syncthreads (vmcnt drain) per K-tile.
// Correctness depends only on the per-K-tile __syncthreads:
//  - ds_reads of buf[cur] are safe: its loads drained at previous sync.
//  - gload_lds into buf[cur^1] is safe: all reads of it finished at the
//    previous sync (it was 'cur' two tiles ago).
// ---------------------------------------------------------------------------
__global__ __launch_bounds__(512) void gemm_kernel(
    const unsigned short* __restrict__ S,
    const unsigned short* __restrict__ Wb,
    const float* __restrict__ bias,
    float* __restrict__ Y) {
  __shared__ __attribute__((aligned(16))) unsigned short As[2][256 * 64];
  __shared__ __attribute__((aligned(16))) unsigned short Bs[2][256 * 64];

  const int tid  = threadIdx.x;
  const int lane = tid & 63;
  const int wid  = tid >> 6;      // 0..7
  const int wm   = wid >> 2;      // 0..1  (M half: 128 rows)
  const int wn   = wid & 3;       // 0..3  (N quarter: 64 cols)

  // XCD-aware swizzle: 784 blocks, 784 % 8 == 0 -> simple bijective form.
  // Each XCD gets 98 consecutive swz ids; swz>>2 = mtile, so the 4 N-tiles
  // of an M-tile are adjacent on one XCD -> S tile L2-shared.
  const int bid   = blockIdx.x;
  const int swz   = (bid & 7) * 98 + (bid >> 3);
  const int mtile = swz >> 2;
  const int ntile = swz & 3;
  const int64_t row0 = (int64_t)mtile * 256;
  const int     c0   = ntile * 256;

  // staging geometry: one issue = 512 threads x 16B = 64 rows x 128B.
  // LDS dest is wave-uniform base (+ lane*16 by HW); swizzle goes on the
  // GLOBAL source column: ((lane&7) ^ (lane>>3)) << 4.
  const int srow = lane >> 3;                 // 0..7
  const int skb  = ((lane & 7) ^ srow) << 4;

  const char* Sg = (const char*)S;
  const char* Wg = (const char*)Wb;

  f32x4 acc[8][4] = {};

  auto stageA = [&](int buf, int k0, int i) {
    const int64_t gr = row0 + i * 64 + wid * 8 + srow;
    __builtin_amdgcn_global_load_lds(
        AS1(Sg + (gr * K_DIM + k0) * 2 + skb),
        AS3((char*)&As[buf][0] + (i * 64 + wid * 8) * 128), 16, 0, 0);
  };
  auto stageB = [&](int buf, int k0, int i) {
    const int64_t gr = (int64_t)c0 + i * 64 + wid * 8 + srow;
    __builtin_amdgcn_global_load_lds(
        AS1(Wg + (gr * K_DIM + k0) * 2 + skb),
        AS3((char*)&Bs[buf][0] + (i * 64 + wid * 8) * 128), 16, 0, 0);
  };

  // prologue: stage K-tile 0 into buf 0
#pragma unroll
  for (int i = 0; i < 4; ++i) stageA(0, 0, i);
#pragma unroll
  for (int i = 0; i < 4; ++i) stageB(0, 0, i);
  __syncthreads();

  const int lr = lane & 15;
  const int lk = (lane >> 4) * 16;
  bf16x8 bfr[4];

  int cur = 0;
  for (int t = 0; t < 8; ++t) {            // 8 K-tiles of 64
    const int  k0n = (t + 1) * 64;
    const bool pf  = (t < 7);
    const int  nxt = cur ^ 1;
    const char* Ab = (const char*)&As[cur][0];
    const char* Bb = (const char*)&Bs[cur][0];

#pragma unroll
    for (int half = 0; half < 2; ++half) { // kk slice of BK=64
      const int kb = half * 64 + lk;
      bf16x8 afr[4];

      // ---- phase (half,0): frags mi 0-3 + B frags ----
#pragma unroll
      for (int mi = 0; mi < 4; ++mi) {
        const int r = wm * 128 + mi * 16 + lr;
        afr[mi] = *(const bf16x8*)(Ab + r * 128 + (kb ^ ((r & 7) << 4)));
      }
#pragma unroll
      for (int nj = 0; nj < 4; ++nj) {
        const int r = wn * 64 + nj * 16 + lr;
        bfr[nj] = *(const bf16x8*)(Bb + r * 128 + (kb ^ ((r & 7) << 4)));
      }
      if (pf) {
        if (half == 0) { stageA(nxt, k0n, 0); stageA(nxt, k0n, 1); }
        else           { stageB(nxt, k0n, 0); stageB(nxt, k0n, 1); }
      }
      __builtin_amdgcn_s_barrier();
      asm volatile("s_waitcnt lgkmcnt(0)" ::: "memory");
      __builtin_amdgcn_sched_barrier(0);
      __builtin_amdgcn_s_setprio(1);
#pragma unroll
      for (int mi = 0; mi < 4; ++mi)
#pragma unroll
        for (int nj = 0; nj < 4; ++nj)
          acc[mi][nj] = __builtin_amdgcn_mfma_f32_16x16x32_bf16(
              afr[mi], bfr[nj], acc[mi][nj], 0, 0, 0);
      __builtin_amdgcn_s_setprio(0);
      __builtin_amdgcn_s_barrier();

      // ---- phase (half,1): frags mi 4-7 (B reused) ----
#pragma unroll
      for (int mi = 0; mi < 4; ++mi) {
        const int r = wm * 128 + (mi + 4) * 16 + lr;
        afr[mi] = *(const bf16x8*)(Ab + r * 128 + (kb ^ ((r & 7) << 4)));
      }
      if (pf) {
        if (half == 0) { stageA(nxt, k0n, 2); stageA(nxt, k0n, 3); }
        else           { stageB(nxt, k0n, 2); stageB(nxt, k0n, 3); }
      }
      __builtin_amdgcn_s_barrier();
      asm volatile("s_waitcnt lgkmcnt(0)" ::: "memory");
      __builtin_amdgcn_sched_barrier(0);
      __builtin_amdgcn_s_setprio(1);
#pragma unroll
      for (int mi = 0; mi < 4; ++mi)
#pragma unroll
        for (int nj = 0; nj < 4; ++nj)
          acc[mi + 4][nj] = __builtin_amdgcn_mfma_f32_16x16x32_bf16(
              afr[mi], bfr[nj], acc[mi + 4][nj], 0, 0, 0);
      __builtin_amdgcn_s_setprio(0);
      __builtin_amdgcn_s_barrier();
    }
    __syncthreads();   // vmcnt(0)+lgkmcnt(0)+barrier: next tile ready,
    cur = nxt;         // and buf[nxt^1] free for the next prefetch
  }

  // epilogue: C/D frag layout col = lane&15, row = (lane>>4)*4 + reg
#pragma unroll
  for (int nj = 0; nj < 4; ++nj) {
    const int c = c0 + wn * 64 + nj * 16 + lr;
    if (c >= C_DIM) continue;
    const float bv = bias[c];
#pragma unroll
    for (int mi = 0; mi < 8; ++mi) {
      const int64_t rb = row0 + wm * 128 + mi * 16 + (lane >> 4) * 4;
#pragma unroll
      for (int r = 0; r < 4; ++r) {
        Y[(rb + r) * (int64_t)C_DIM + c] = acc[mi][nj][r] + bv;
      }
    }
  }
}

// ---------------------------------------------------------------------------
extern "C" void kernel_launch(void* const* d_in, const int* in_sizes, int n_in,
                              void* d_out, int out_size, void* d_ws, size_t ws_size,
                              hipStream_t stream) {
  const float* x = (const float*)d_in[0];
  const float* W = (const float*)d_in[1];
  const float* b = (const float*)d_in[2];
  float* Y = (float*)d_out;

  unsigned short* S  = (unsigned short*)d_ws;            // 50176*512 bf16 = 51.4 MB
  unsigned short* Wb = S + (size_t)M_ROWS * K_DIM;       // 1024*512 bf16  =  1.0 MB

  hipLaunchKernelGGL(wconv_kernel, dim3(512), dim3(256), 0, stream, W, Wb);
  hipLaunchKernelGGL(lif_kernel, dim3(2048), dim3(256), 0, stream, x, S);
  hipLaunchKernelGGL(gemm_kernel, dim3(784), dim3(512), 0, stream, S, Wb, b, Y);
}